// Round 4
// baseline (218.875 us; speedup 1.0000x reference)
//
#include <hip/hip_runtime.h>
#include <hip/hip_bf16.h>
#include <stdint.h>

typedef __bf16 bf16x8 __attribute__((ext_vector_type(8)));
typedef float  f32x4  __attribute__((ext_vector_type(4)));

#define M_ROWS 8192
#define K_DIM  2048
#define HIDN   1024
#define BM 256
#define BN 256
#define BK 64

__device__ __forceinline__ unsigned short f2bf(float f) {
    __hip_bfloat16 h = __float2bfloat16(f);
    return *reinterpret_cast<unsigned short*>(&h);
}

// ---------------- pack kernels (unchanged, verified) ----------------
__global__ __launch_bounds__(256) void pack_a_kernel(const float* __restrict__ x,
                                                     const float* __restrict__ h0,
                                                     unsigned short* __restrict__ A) {
    int idx = blockIdx.x * 256 + threadIdx.x;
    int row = idx >> 9;
    int col = (idx & 511) << 2;
    const float* src = (col < HIDN) ? (x + (int64_t)row * HIDN + col)
                                    : (h0 + (int64_t)row * HIDN + (col - HIDN));
    float4 v = *reinterpret_cast<const float4*>(src);
    ushort4 o;
    o.x = f2bf(v.x); o.y = f2bf(v.y); o.z = f2bf(v.z); o.w = f2bf(v.w);
    *reinterpret_cast<ushort4*>(A + (int64_t)idx * 4) = o;
}

// B'[4096][2048] bf16, rows permuted: j -> gate g=(j>>4)&3, h=(j>>6)*16+(j&15)
__global__ __launch_bounds__(256) void pack_b_kernel(const float* __restrict__ Wx,
                                                     const float* __restrict__ Wh,
                                                     unsigned short* __restrict__ Bp) {
    int idx = blockIdx.x * 256 + threadIdx.x;
    int j   = idx >> 9;
    int col = (idx & 511) << 2;
    int g   = (j >> 4) & 3;
    int hh  = ((j >> 6) << 4) | (j & 15);
    int r   = g * HIDN + hh;
    const float* src = (col < HIDN) ? (Wx + (int64_t)r * HIDN + col)
                                    : (Wh + (int64_t)r * HIDN + (col - HIDN));
    float4 v = *reinterpret_cast<const float4*>(src);
    ushort4 o;
    o.x = f2bf(v.x); o.y = f2bf(v.y); o.z = f2bf(v.z); o.w = f2bf(v.w);
    *reinterpret_cast<ushort4*>(Bp + (int64_t)j * K_DIM + col) = o;
}

// ---------------- persistent 256x256x2 8-phase GEMM ----------------
// Each block computes TWO n-tiles (bn=2p, 2p+1) over a 64-virtual-tile K-loop;
// pipeline never drains at the t0->t1 transition. LDS/swizzle as R3 (verified:
// 0 bank conflicts): region(buf,mat,kh) = buf*32768+mat*16384+kh*8192,
// [256 rows][32 k] bf16, 16B-chunk swizzle slot ^= (row>>1)&3 on both sides.

__device__ __forceinline__ void stg2(unsigned short* r_, const unsigned short* gt,
                                     int64_t soff0, int64_t soff1, int l0, int l1) {
    __builtin_amdgcn_global_load_lds(
        (const __attribute__((address_space(1))) unsigned int*)(gt + soff0),
        (__attribute__((address_space(3))) unsigned int*)(r_ + l0), 16, 0, 0);
    __builtin_amdgcn_global_load_lds(
        (const __attribute__((address_space(1))) unsigned int*)(gt + soff1),
        (__attribute__((address_space(3))) unsigned int*)(r_ + l1), 16, 0, 0);
}

__global__ __launch_bounds__(512, 2) void lstm_gemm_kernel(
    const unsigned short* __restrict__ A, const unsigned short* __restrict__ Bp,
    const float* __restrict__ bx, const float* __restrict__ bh,
    const float* __restrict__ c0, float* __restrict__ out)
{
    __shared__ alignas(16) unsigned short smem[65536];   // 128 KB

    const int tid  = threadIdx.x;
    const int wid  = tid >> 6;
    const int lane = tid & 63;

    // 2D XCD chunking over 256 blocks: 32 bm x 8 bnp; xcd owns 8bm x 4bnp.
    const int bid = blockIdx.x;
    const int xcd = bid & 7;
    const int idx = bid >> 3;                  // 0..31
    const int bm  = (xcd & 3) * 8 + (idx & 7);
    const int bnp = (xcd >> 2) * 4 + (idx >> 3);
    const int bn0 = 2 * bnp;
    const int bn1 = 2 * bnp + 1;
    const int m0  = bm * BM;
    const int wm  = wid >> 2;                  // 0..1
    const int wn  = wid & 3;                   // 0..3

    const unsigned short* Ag  = A  + (int64_t)m0 * K_DIM;
    const unsigned short* Bg0 = Bp + (int64_t)bn0 * BN * K_DIM;
    const unsigned short* Bg1 = Bp + (int64_t)bn1 * BN * K_DIM;

    // staging constants: chunk c = ld*512 + wid*64 + lane; row = c>>2
    const int c0_ = wid * 64 + lane;
    const int c1_ = 512 + c0_;
    const int64_t soff0 = (int64_t)(c0_ >> 2) * K_DIM + (int64_t)((((c0_ & 3) ^ ((c0_ >> 3) & 3))) * 8);
    const int64_t soff1 = (int64_t)(c1_ >> 2) * K_DIM + (int64_t)((((c1_ & 3) ^ ((c1_ >> 3) & 3))) * 8);
    const int l0 = (c0_ & ~63) * 8;
    const int l1 = (c1_ & ~63) * 8;

    // ds_read fragment offsets (region-relative, shorts)
    int offA[8], offB[4];
#pragma unroll
    for (int m = 0; m < 8; ++m) {
        const int row = wm * 128 + m * 16 + (lane & 15);
        offA[m] = row * 32 + (((lane >> 4) ^ (row >> 1)) & 3) * 8;
    }
#pragma unroll
    for (int n = 0; n < 4; ++n) {
        const int row = wn * 64 + n * 16 + (lane & 15);
        offB[n] = row * 32 + (((lane >> 4) ^ (row >> 1)) & 3) * 8;
    }

    f32x4 acc[8][4] = {};
    bf16x8 aF[4], bF[4];

#define REGP(buf, mat, kh) (smem + (buf) * 32768 + (mat) * 16384 + (kh) * 8192)
#define LOAD_A(buf, kh, mh) { \
    const unsigned short* r_ = REGP(buf, 0, kh); \
    _Pragma("unroll") for (int m_ = 0; m_ < 4; ++m_) \
        aF[m_] = *reinterpret_cast<const bf16x8*>(r_ + offA[(mh) * 4 + m_]); }
#define LOAD_B(buf, kh) { \
    const unsigned short* r_ = REGP(buf, 1, kh); \
    _Pragma("unroll") for (int n_ = 0; n_ < 4; ++n_) \
        bF[n_] = *reinterpret_cast<const bf16x8*>(r_ + offB[n_]); }
#define MFMA16(mh) { \
    _Pragma("unroll") for (int m_ = 0; m_ < 4; ++m_) \
    _Pragma("unroll") for (int n_ = 0; n_ < 4; ++n_) \
        acc[(mh) * 4 + m_][n_] = __builtin_amdgcn_mfma_f32_16x16x32_bf16(aF[m_], bF[n_], acc[(mh) * 4 + m_][n_], 0, 0, 0); }
#define STG(buf, mat, kh, gt) stg2(REGP(buf, mat, kh), (gt), soff0, soff1, l0, l1)
#define VM6() asm volatile("s_waitcnt vmcnt(6)" ::: "memory")
#define PH_PRE()  { __builtin_amdgcn_s_barrier(); \
                    asm volatile("s_waitcnt lgkmcnt(0)" ::: "memory"); \
                    __builtin_amdgcn_sched_barrier(0); \
                    __builtin_amdgcn_s_setprio(1); }
#define PH_POST() { __builtin_amdgcn_s_setprio(0); \
                    __builtin_amdgcn_sched_barrier(0); \
                    __builtin_amdgcn_s_barrier(); }

// one steady iteration: computes buf0/buf1, stages per the verified R3 pattern
#define STEADY_BODY(A1, A2, A3, B2, B3) { \
    LOAD_A(0, 0, 0); LOAD_B(0, 0); STG(1, 0, 1, (A1) + 32); PH_PRE(); MFMA16(0); PH_POST(); \
    LOAD_A(0, 0, 1);               STG(0, 1, 0, (B2));      PH_PRE(); MFMA16(1); PH_POST(); \
    LOAD_A(0, 1, 0); LOAD_B(0, 1); STG(0, 0, 0, (A2));      PH_PRE(); MFMA16(0); PH_POST(); \
    LOAD_A(0, 1, 1);               STG(0, 1, 1, (B2) + 32); VM6(); PH_PRE(); MFMA16(1); PH_POST(); \
    LOAD_A(1, 0, 0); LOAD_B(1, 0); STG(0, 0, 1, (A2) + 32); PH_PRE(); MFMA16(0); PH_POST(); \
    LOAD_A(1, 0, 1);               STG(1, 1, 0, (B3));      PH_PRE(); MFMA16(1); PH_POST(); \
    LOAD_A(1, 1, 0); LOAD_B(1, 1); STG(1, 0, 0, (A3));      PH_PRE(); MFMA16(0); PH_POST(); \
    LOAD_A(1, 1, 1);               STG(1, 1, 1, (B3) + 32); VM6(); PH_PRE(); MFMA16(1); PH_POST(); }

// fused LSTM epilogue for n-origin N0 (= bn*256); reads acc, c0; writes h1,c1
#define EPILOGUE(N0) { \
    const int h = ((N0) >> 2) + wn * 16 + (lane & 15); \
    const float bi  = bx[h]            + bh[h]; \
    const float bff = bx[HIDN + h]     + bh[HIDN + h]; \
    const float bc  = bx[2 * HIDN + h] + bh[2 * HIDN + h]; \
    const float bo  = bx[3 * HIDN + h] + bh[3 * HIDN + h]; \
    _Pragma("unroll") for (int m = 0; m < 8; ++m) { \
        const int rowb = m0 + wm * 128 + m * 16 + ((lane >> 4) << 2); \
        _Pragma("unroll") for (int r = 0; r < 4; ++r) { \
            const int row = rowb + r; \
            const float gi = acc[m][0][r] + bi; \
            const float gf = acc[m][1][r] + bff; \
            const float gc = acc[m][2][r] + bc; \
            const float go = acc[m][3][r] + bo; \
            const float si = 1.f / (1.f + __expf(-gi)); \
            const float sf = 1.f / (1.f + __expf(-gf)); \
            const float tc = 1.f - 2.f / (__expf(2.f * gc) + 1.f); \
            const float so = 1.f / (1.f + __expf(-go)); \
            const float c0v = c0[(int64_t)row * HIDN + h]; \
            const float c1 = sf * c0v + si * tc; \
            const float th = 1.f - 2.f / (__expf(2.f * c1) + 1.f); \
            out[(int64_t)row * HIDN + h] = so * th; \
            out[(int64_t)M_ROWS * HIDN + (int64_t)row * HIDN + h] = c1; \
        } } }

    // ---- prologue: vt0 all 4 halves, vmcnt(4), vt1 first 3 halves, vmcnt(6) ----
    STG(0, 1, 0, Bg0);            // vt0.B-kh0
    STG(0, 0, 0, Ag);             // vt0.A-kh0
    STG(0, 1, 1, Bg0 + 32);       // vt0.B-kh1
    STG(0, 0, 1, Ag + 32);        // vt0.A-kh1
    asm volatile("s_waitcnt vmcnt(4)" ::: "memory");
    STG(1, 1, 0, Bg0 + 64);       // vt1.B-kh0
    STG(1, 0, 0, Ag + 64);        // vt1.A-kh0
    STG(1, 1, 1, Bg0 + 96);       // vt1.B-kh1
    asm volatile("s_waitcnt vmcnt(6)" ::: "memory");
    __builtin_amdgcn_s_barrier();

    // ---- t0 steady loop: vt 0..29 computed, staging vt1..31 (all Bg0) ----
    for (int i = 0; i < 15; ++i) {
        const unsigned short* A1 = Ag + (2 * i + 1) * 64;
        const unsigned short* A2 = Ag + (2 * i + 2) * 64;
        const unsigned short* A3 = Ag + (2 * i + 3) * 64;
        const unsigned short* B2 = Bg0 + (2 * i + 2) * 64;
        const unsigned short* B3 = Bg0 + (2 * i + 3) * 64;
        STEADY_BODY(A1, A2, A3, B2, B3);
    }

    // ---- transition iter: computes vt30,31 (t0's last); stages vt32,33 = t1 tiles 0,1 ----
    // A-tiles wrap (A panel reused for t1); B switches to Bg1. Pipeline stays full.
    STEADY_BODY(Ag + 31 * 64, Ag, Ag + 64, Bg1, Bg1 + 64);

    // ---- t0 epilogue (between barriers; waves re-sync at next PH_PRE).
    // Subsequent counted vmcnt(6) waits also cover these stores (L2-ack, fast).
    EPILOGUE(bn0 * BN);

#pragma unroll
    for (int m = 0; m < 8; ++m)
#pragma unroll
        for (int n = 0; n < 4; ++n)
            acc[m][n] = (f32x4){0.f, 0.f, 0.f, 0.f};

    // ---- t1 steady loop: vt 32..61 computed, staging vt33..63 (all Bg1) ----
    for (int i = 0; i < 15; ++i) {
        const unsigned short* A1 = Ag + (2 * i + 1) * 64;
        const unsigned short* A2 = Ag + (2 * i + 2) * 64;
        const unsigned short* A3 = Ag + (2 * i + 3) * 64;
        const unsigned short* B2 = Bg1 + (2 * i + 2) * 64;
        const unsigned short* B3 = Bg1 + (2 * i + 3) * 64;
        STEADY_BODY(A1, A2, A3, B2, B3);
    }

    // ---- final iteration (vt 62,63): only tile31.A-kh1 left to stage ----
    {
        LOAD_A(0, 0, 0); LOAD_B(0, 0);
        STG(1, 0, 1, Ag + 31 * 64 + 32);
        PH_PRE(); MFMA16(0); PH_POST();
        LOAD_A(0, 0, 1);
        PH_PRE(); MFMA16(1); PH_POST();
        LOAD_A(0, 1, 0); LOAD_B(0, 1);
        PH_PRE(); MFMA16(0); PH_POST();
        LOAD_A(0, 1, 1);
        asm volatile("s_waitcnt vmcnt(0)" ::: "memory");
        PH_PRE(); MFMA16(1); PH_POST();
        LOAD_A(1, 0, 0); LOAD_B(1, 0);
        PH_PRE(); MFMA16(0); PH_POST();
        LOAD_A(1, 0, 1);
        PH_PRE(); MFMA16(1); PH_POST();
        LOAD_A(1, 1, 0); LOAD_B(1, 1);
        PH_PRE(); MFMA16(0); PH_POST();
        LOAD_A(1, 1, 1);
        PH_PRE(); MFMA16(1);
        __builtin_amdgcn_s_setprio(0);
    }

    // ---- t1 epilogue ----
    EPILOGUE(bn1 * BN);
}

extern "C" void kernel_launch(void* const* d_in, const int* in_sizes, int n_in,
                              void* d_out, int out_size, void* d_ws, size_t ws_size,
                              hipStream_t stream) {
    const float* x  = (const float*)d_in[0];
    const float* h0 = (const float*)d_in[1];
    const float* c0 = (const float*)d_in[2];
    const float* Wx = (const float*)d_in[3];
    const float* bx = (const float*)d_in[4];
    const float* Wh = (const float*)d_in[5];
    const float* bh = (const float*)d_in[6];
    float* out = (float*)d_out;

    unsigned short* A = (unsigned short*)d_ws;                       // 33.5 MB
    unsigned short* B = A + (size_t)M_ROWS * K_DIM;                  // 16.8 MB

    pack_a_kernel<<<dim3(16384), dim3(256), 0, stream>>>(x, h0, A);
    pack_b_kernel<<<dim3(8192),  dim3(256), 0, stream>>>(Wx, Wh, B);
    lstm_gemm_kernel<<<dim3(256), dim3(512), 0, stream>>>(A, B, bx, bh, c0, out);
}

// Round 5
// 177.399 us; speedup vs baseline: 1.2338x; 1.2338x over previous
//
#include <hip/hip_runtime.h>
#include <hip/hip_bf16.h>
#include <stdint.h>

typedef __bf16 bf16x8 __attribute__((ext_vector_type(8)));
typedef float  f32x16 __attribute__((ext_vector_type(16)));

#define M_ROWS 8192
#define K_DIM  2048
#define HIDN   1024
#define BM 256
#define BN 256
#define BK 64
#define NTILES (K_DIM / BK)   /* 32 */
#define NITER  (NTILES / 2)   /* 16 */

__device__ __forceinline__ unsigned short f2bf(float f) {
    __hip_bfloat16 h = __float2bfloat16(f);
    return *reinterpret_cast<unsigned short*>(&h);
}

// ---------------- pack kernels ----------------
__global__ __launch_bounds__(256) void pack_a_kernel(const float* __restrict__ x,
                                                     const float* __restrict__ h0,
                                                     unsigned short* __restrict__ A) {
    int idx = blockIdx.x * 256 + threadIdx.x;
    int row = idx >> 9;
    int col = (idx & 511) << 2;
    const float* src = (col < HIDN) ? (x + (int64_t)row * HIDN + col)
                                    : (h0 + (int64_t)row * HIDN + (col - HIDN));
    float4 v = *reinterpret_cast<const float4*>(src);
    ushort4 o;
    o.x = f2bf(v.x); o.y = f2bf(v.y); o.z = f2bf(v.z); o.w = f2bf(v.w);
    *reinterpret_cast<ushort4*>(A + (int64_t)idx * 4) = o;
}

// B'[4096][2048] bf16, rows permuted for 32x32 fragments: within each 128-col
// wave strip, 32-col blocks are gates 0..3 for the same 32 h values:
//   j -> g=(j>>5)&3, h=(j>>7)*32+(j&31); source row r = g*1024 + h.
__global__ __launch_bounds__(256) void pack_b_kernel(const float* __restrict__ Wx,
                                                     const float* __restrict__ Wh,
                                                     unsigned short* __restrict__ Bp) {
    int idx = blockIdx.x * 256 + threadIdx.x;
    int j   = idx >> 9;
    int col = (idx & 511) << 2;
    int g   = (j >> 5) & 3;
    int hh  = ((j >> 7) << 5) | (j & 31);
    int r   = g * HIDN + hh;
    const float* src = (col < HIDN) ? (Wx + (int64_t)r * HIDN + col)
                                    : (Wh + (int64_t)r * HIDN + (col - HIDN));
    float4 v = *reinterpret_cast<const float4*>(src);
    ushort4 o;
    o.x = f2bf(v.x); o.y = f2bf(v.y); o.z = f2bf(v.z); o.w = f2bf(v.w);
    *reinterpret_cast<ushort4*>(Bp + (int64_t)j * K_DIM + col) = o;
}

// ---------------- 256x256 8-phase GEMM, 32x32x16 MFMA ----------------
// LDS: 8 regions of 16KB: region(buf,mat,kh) = buf*32768+mat*16384+kh*8192
// Region [256 rows][32 k] bf16 (64B rows); 16B-chunk swizzle slot ^= (row>>1)&3
// on BOTH pre-swizzled global source and ds_read (verified 0 conflicts, R3).
// Waves: 4m x 2n; per-wave tile 64x128; acc[mh][g] f32x16, g = gate (lane-local).

__device__ __forceinline__ void stg2(unsigned short* r_, const unsigned short* gt,
                                     int64_t soff0, int64_t soff1, int l0, int l1) {
    __builtin_amdgcn_global_load_lds(
        (const __attribute__((address_space(1))) unsigned int*)(gt + soff0),
        (__attribute__((address_space(3))) unsigned int*)(r_ + l0), 16, 0, 0);
    __builtin_amdgcn_global_load_lds(
        (const __attribute__((address_space(1))) unsigned int*)(gt + soff1),
        (__attribute__((address_space(3))) unsigned int*)(r_ + l1), 16, 0, 0);
}

__global__ __launch_bounds__(512, 2) void lstm_gemm_kernel(
    const unsigned short* __restrict__ A, const unsigned short* __restrict__ Bp,
    const float* __restrict__ bx, const float* __restrict__ bh,
    const float* __restrict__ c0, float* __restrict__ out)
{
    __shared__ alignas(16) unsigned short smem[65536];   // 128 KB

    const int tid  = threadIdx.x;
    const int wid  = tid >> 6;
    const int lane = tid & 63;

    // 2D XCD chunking: grid 32(bm) x 16(bn) = 512; xcd owns 8bm x 8bn.
    const int bid = blockIdx.x;
    const int xcd = bid & 7;
    const int idx = bid >> 3;            // 0..63
    const int bm  = (xcd & 3) * 8 + (idx & 7);
    const int bn  = (xcd >> 2) * 8 + (idx >> 3);
    const int m0  = bm * BM;
    const int n0  = bn * BN;
    const int wm  = wid >> 1;            // 0..3  (m-offset wm*64)
    const int wn  = wid & 1;             // 0..1  (n-offset wn*128)

    const unsigned short* Ag = A  + (int64_t)m0 * K_DIM;
    const unsigned short* Bg = Bp + (int64_t)n0 * K_DIM;

    // staging constants: chunk c = ld*512 + wid*64 + lane; row = c>>2
    const int c0_ = wid * 64 + lane;
    const int c1_ = 512 + c0_;
    const int64_t soff0 = (int64_t)(c0_ >> 2) * K_DIM + (int64_t)((((c0_ & 3) ^ ((c0_ >> 3) & 3))) * 8);
    const int64_t soff1 = (int64_t)(c1_ >> 2) * K_DIM + (int64_t)((((c1_ & 3) ^ ((c1_ >> 3) & 3))) * 8);
    const int l0 = (c0_ & ~63) * 8;
    const int l1 = (c1_ & ~63) * 8;

    // ds_read fragment offsets (region-relative, shorts), loop-invariant.
    // A frag (mh, ks): row = wm*64 + mh*32 + (lane&31); slot q = (lane>>5) + 2*ks
    // B frag (g, ks):  row = wn*128 + g*32 + (lane&31); same slot math
    int offA[4], offB[8];
#pragma unroll
    for (int mh = 0; mh < 2; ++mh)
#pragma unroll
        for (int ks = 0; ks < 2; ++ks) {
            const int row = wm * 64 + mh * 32 + (lane & 31);
            const int q   = (lane >> 5) + 2 * ks;
            offA[mh * 2 + ks] = row * 32 + ((q ^ (row >> 1)) & 3) * 8;
        }
#pragma unroll
    for (int g = 0; g < 4; ++g)
#pragma unroll
        for (int ks = 0; ks < 2; ++ks) {
            const int row = wn * 128 + g * 32 + (lane & 31);
            const int q   = (lane >> 5) + 2 * ks;
            offB[g * 2 + ks] = row * 32 + ((q ^ (row >> 1)) & 3) * 8;
        }

    f32x16 acc[2][4] = {};               // [mh][gate]
    bf16x8 aF[2], bF[8];

#define REGP(buf, mat, kh) (smem + (buf) * 32768 + (mat) * 16384 + (kh) * 8192)
#define LOAD_A(buf, kh, mh) { \
    const unsigned short* r_ = REGP(buf, 0, kh); \
    aF[0] = *reinterpret_cast<const bf16x8*>(r_ + offA[(mh) * 2 + 0]); \
    aF[1] = *reinterpret_cast<const bf16x8*>(r_ + offA[(mh) * 2 + 1]); }
#define LOAD_B(buf, kh) { \
    const unsigned short* r_ = REGP(buf, 1, kh); \
    _Pragma("unroll") for (int n_ = 0; n_ < 8; ++n_) \
        bF[n_] = *reinterpret_cast<const bf16x8*>(r_ + offB[n_]); }
#define MFMA8(mh) { \
    _Pragma("unroll") for (int g_ = 0; g_ < 4; ++g_) { \
        acc[mh][g_] = __builtin_amdgcn_mfma_f32_32x32x16_bf16(aF[0], bF[2 * g_],     acc[mh][g_], 0, 0, 0); \
        acc[mh][g_] = __builtin_amdgcn_mfma_f32_32x32x16_bf16(aF[1], bF[2 * g_ + 1], acc[mh][g_], 0, 0, 0); } }
#define STG(buf, mat, kh, gt) stg2(REGP(buf, mat, kh), (gt), soff0, soff1, l0, l1)
#define VM6() asm volatile("s_waitcnt vmcnt(6)" ::: "memory")
#define PH_PRE()  { __builtin_amdgcn_s_barrier(); \
                    asm volatile("s_waitcnt lgkmcnt(0)" ::: "memory"); \
                    __builtin_amdgcn_sched_barrier(0); \
                    __builtin_amdgcn_s_setprio(1); }
#define PH_POST() { __builtin_amdgcn_s_setprio(0); \
                    __builtin_amdgcn_sched_barrier(0); \
                    __builtin_amdgcn_s_barrier(); }

    // ---- prologue: tile0 all 4 halves, vmcnt(4), tile1 first 3 halves, vmcnt(6) ----
    STG(0, 1, 0, Bg);            // t0.B-kh0
    STG(0, 0, 0, Ag);            // t0.A-kh0
    STG(0, 1, 1, Bg + 32);       // t0.B-kh1
    STG(0, 0, 1, Ag + 32);       // t0.A-kh1
    asm volatile("s_waitcnt vmcnt(4)" ::: "memory");
    STG(1, 1, 0, Bg + 64);       // t1.B-kh0
    STG(1, 0, 0, Ag + 64);       // t1.A-kh0
    STG(1, 1, 1, Bg + 96);       // t1.B-kh1
    asm volatile("s_waitcnt vmcnt(6)" ::: "memory");
    __builtin_amdgcn_s_barrier();

    // ---- main loop: iter i computes tiles 2i (buf0) and 2i+1 (buf1) ----
    for (int i = 0; i < NITER - 1; ++i) {
        const unsigned short* At1 = Ag + (2 * i + 1) * 64;
        const unsigned short* At2 = Ag + (2 * i + 2) * 64;
        const unsigned short* At3 = Ag + (2 * i + 3) * 64;
        const unsigned short* Bt2 = Bg + (2 * i + 2) * 64;
        const unsigned short* Bt3 = Bg + (2 * i + 3) * 64;

        // ph1
        LOAD_A(0, 0, 0); LOAD_B(0, 0);
        STG(1, 0, 1, At1 + 32);
        PH_PRE(); MFMA8(0); PH_POST();
        // ph2
        LOAD_A(0, 0, 1);
        STG(0, 1, 0, Bt2);
        PH_PRE(); MFMA8(1); PH_POST();
        // ph3
        LOAD_A(0, 1, 0); LOAD_B(0, 1);
        STG(0, 0, 0, At2);
        PH_PRE(); MFMA8(0); PH_POST();
        // ph4
        LOAD_A(0, 1, 1);
        STG(0, 1, 1, Bt2 + 32);
        VM6();
        PH_PRE(); MFMA8(1); PH_POST();
        // ph5
        LOAD_A(1, 0, 0); LOAD_B(1, 0);
        STG(0, 0, 1, At2 + 32);
        PH_PRE(); MFMA8(0); PH_POST();
        // ph6
        LOAD_A(1, 0, 1);
        STG(1, 1, 0, Bt3);
        PH_PRE(); MFMA8(1); PH_POST();
        // ph7
        LOAD_A(1, 1, 0); LOAD_B(1, 1);
        STG(1, 0, 0, At3);
        PH_PRE(); MFMA8(0); PH_POST();
        // ph8
        LOAD_A(1, 1, 1);
        STG(1, 1, 1, Bt3 + 32);
        VM6();
        PH_PRE(); MFMA8(1); PH_POST();
    }

    // ---- final iteration (tiles 30, 31): only t31.A-kh1 left to stage ----
    {
        LOAD_A(0, 0, 0); LOAD_B(0, 0);
        STG(1, 0, 1, Ag + 31 * 64 + 32);
        PH_PRE(); MFMA8(0); PH_POST();
        LOAD_A(0, 0, 1);
        PH_PRE(); MFMA8(1); PH_POST();
        LOAD_A(0, 1, 0); LOAD_B(0, 1);
        PH_PRE(); MFMA8(0); PH_POST();
        LOAD_A(0, 1, 1);
        asm volatile("s_waitcnt vmcnt(0)" ::: "memory");
        PH_PRE(); MFMA8(1); PH_POST();
        LOAD_A(1, 0, 0); LOAD_B(1, 0);
        PH_PRE(); MFMA8(0); PH_POST();
        LOAD_A(1, 0, 1);
        PH_PRE(); MFMA8(1); PH_POST();
        LOAD_A(1, 1, 0); LOAD_B(1, 1);
        PH_PRE(); MFMA8(0); PH_POST();
        LOAD_A(1, 1, 1);
        PH_PRE(); MFMA8(1);
        __builtin_amdgcn_s_setprio(0);
    }

    // ---- fused LSTM epilogue (32x32 C/D layout: col=lane&31,
    //      row = (reg&3) + 8*(reg>>2) + 4*(lane>>5)) ----
    const int h = (n0 >> 2) + wn * 32 + (lane & 31);
    const float bi  = bx[h]            + bh[h];
    const float bff = bx[HIDN + h]     + bh[HIDN + h];
    const float bc  = bx[2 * HIDN + h] + bh[2 * HIDN + h];
    const float bo  = bx[3 * HIDN + h] + bh[3 * HIDN + h];

#pragma unroll
    for (int mh = 0; mh < 2; ++mh) {
        const int rowb = m0 + wm * 64 + mh * 32 + ((lane >> 5) << 2);
#pragma unroll
        for (int reg = 0; reg < 16; ++reg) {
            const int row = rowb + (reg & 3) + 8 * (reg >> 2);
            const float gi = acc[mh][0][reg] + bi;
            const float gf = acc[mh][1][reg] + bff;
            const float gc = acc[mh][2][reg] + bc;
            const float go = acc[mh][3][reg] + bo;
            const float si = 1.f / (1.f + __expf(-gi));
            const float sf = 1.f / (1.f + __expf(-gf));
            const float tc = 1.f - 2.f / (__expf(2.f * gc) + 1.f);
            const float so = 1.f / (1.f + __expf(-go));
            const float c0v = c0[(int64_t)row * HIDN + h];
            const float c1 = sf * c0v + si * tc;
            const float th = 1.f - 2.f / (__expf(2.f * c1) + 1.f);
            out[(int64_t)row * HIDN + h] = so * th;                        // h1
            out[(int64_t)M_ROWS * HIDN + (int64_t)row * HIDN + h] = c1;    // c1
        }
    }
}

extern "C" void kernel_launch(void* const* d_in, const int* in_sizes, int n_in,
                              void* d_out, int out_size, void* d_ws, size_t ws_size,
                              hipStream_t stream) {
    const float* x  = (const float*)d_in[0];
    const float* h0 = (const float*)d_in[1];
    const float* c0 = (const float*)d_in[2];
    const float* Wx = (const float*)d_in[3];
    const float* bx = (const float*)d_in[4];
    const float* Wh = (const float*)d_in[5];
    const float* bh = (const float*)d_in[6];
    float* out = (float*)d_out;

    unsigned short* A = (unsigned short*)d_ws;                       // 33.5 MB
    unsigned short* B = A + (size_t)M_ROWS * K_DIM;                  // 16.8 MB

    pack_a_kernel<<<dim3(16384), dim3(256), 0, stream>>>(x, h0, A);
    pack_b_kernel<<<dim3(8192),  dim3(256), 0, stream>>>(Wx, Wh, B);
    lstm_gemm_kernel<<<dim3(512), dim3(512), 0, stream>>>(A, B, bx, bh, c0, out);
}

// Round 6
// 159.954 us; speedup vs baseline: 1.3684x; 1.1091x over previous
//
#include <hip/hip_runtime.h>
#include <hip/hip_bf16.h>
#include <stdint.h>

typedef __bf16 bf16x8 __attribute__((ext_vector_type(8)));
typedef float  f32x4  __attribute__((ext_vector_type(4)));

#define M_ROWS 8192
#define K_DIM  2048
#define HIDN   1024
#define BM 256
#define BN 256
#define BK 64
#define NTILES (K_DIM / BK)   /* 32 */
#define NITER  (NTILES / 2)   /* 16 */

__device__ __forceinline__ unsigned short f2bf(float f) {
    __hip_bfloat16 h = __float2bfloat16(f);
    return *reinterpret_cast<unsigned short*>(&h);
}

// ---------------- fused pack kernel ----------------
// blocks [0, 16384): A[8192][2048] bf16 = [x | h0]
// blocks [16384, 24576): B'[4096][2048] bf16, rows permuted:
//   j -> gate g=(j>>4)&3, h=(j>>6)*16+(j&15); source row r = g*1024 + h.
__global__ __launch_bounds__(256) void pack_kernel(const float* __restrict__ x,
                                                   const float* __restrict__ h0,
                                                   const float* __restrict__ Wx,
                                                   const float* __restrict__ Wh,
                                                   unsigned short* __restrict__ A,
                                                   unsigned short* __restrict__ Bp) {
    if (blockIdx.x < 16384) {
        int idx = blockIdx.x * 256 + threadIdx.x;
        int row = idx >> 9;
        int col = (idx & 511) << 2;
        const float* src = (col < HIDN) ? (x + (int64_t)row * HIDN + col)
                                        : (h0 + (int64_t)row * HIDN + (col - HIDN));
        float4 v = *reinterpret_cast<const float4*>(src);
        ushort4 o;
        o.x = f2bf(v.x); o.y = f2bf(v.y); o.z = f2bf(v.z); o.w = f2bf(v.w);
        *reinterpret_cast<ushort4*>(A + (int64_t)idx * 4) = o;
    } else {
        int idx = (blockIdx.x - 16384) * 256 + threadIdx.x;
        int j   = idx >> 9;
        int col = (idx & 511) << 2;
        int g   = (j >> 4) & 3;
        int hh  = ((j >> 6) << 4) | (j & 15);
        int r   = g * HIDN + hh;
        const float* src = (col < HIDN) ? (Wx + (int64_t)r * HIDN + col)
                                        : (Wh + (int64_t)r * HIDN + (col - HIDN));
        float4 v = *reinterpret_cast<const float4*>(src);
        ushort4 o;
        o.x = f2bf(v.x); o.y = f2bf(v.y); o.z = f2bf(v.z); o.w = f2bf(v.w);
        *reinterpret_cast<ushort4*>(Bp + (int64_t)j * K_DIM + col) = o;
    }
}

// ---------------- 256x256 8-phase GEMM (R3-verified structure) ----------------
// LDS: 8 regions of 16KB: region(buf,mat,kh) = buf*32768+mat*16384+kh*8192
// Region layout [256 rows][32 k] bf16 (64B rows). 16B-chunk swizzle:
//   lds_slot s of row r holds logical slot s ^ ((r>>1)&3)
// applied on BOTH the pre-swizzled global source and the ds_read address.
// (Verified R3: SQ_LDS_BANK_CONFLICT == 0.)

__device__ __forceinline__ void stg2(unsigned short* r_, const unsigned short* gt,
                                     int64_t soff0, int64_t soff1, int l0, int l1) {
    __builtin_amdgcn_global_load_lds(
        (const __attribute__((address_space(1))) unsigned int*)(gt + soff0),
        (__attribute__((address_space(3))) unsigned int*)(r_ + l0), 16, 0, 0);
    __builtin_amdgcn_global_load_lds(
        (const __attribute__((address_space(1))) unsigned int*)(gt + soff1),
        (__attribute__((address_space(3))) unsigned int*)(r_ + l1), 16, 0, 0);
}

__global__ __launch_bounds__(512, 2) void lstm_gemm_kernel(
    const unsigned short* __restrict__ A, const unsigned short* __restrict__ Bp,
    const float* __restrict__ bx, const float* __restrict__ bh,
    const float* __restrict__ c0, float* __restrict__ out)
{
    __shared__ alignas(16) unsigned short smem[65536];   // 128 KB

    const int tid  = threadIdx.x;
    const int wid  = tid >> 6;
    const int lane = tid & 63;

    // 2D XCD chunking: grid 32(bm) x 16(bn) = 512; xcd owns 8bm x 8bn.
    const int bid = blockIdx.x;
    const int xcd = bid & 7;
    const int idx = bid >> 3;            // 0..63
    const int bm  = (xcd & 3) * 8 + (idx & 7);
    const int bn  = (xcd >> 2) * 8 + (idx >> 3);
    const int m0  = bm * BM;
    const int n0  = bn * BN;
    const int wm  = wid >> 2;            // 0..1
    const int wn  = wid & 3;             // 0..3

    const unsigned short* Ag = A  + (int64_t)m0 * K_DIM;
    const unsigned short* Bg = Bp + (int64_t)n0 * K_DIM;

    // staging constants: chunk c = ld*512 + wid*64 + lane; row = c>>2
    // pre-swizzled source slot = (c&3) ^ ((c>>3)&3)   [(c>>3)&3 == (row>>1)&3]
    const int c0_ = wid * 64 + lane;
    const int c1_ = 512 + c0_;
    const int64_t soff0 = (int64_t)(c0_ >> 2) * K_DIM + (int64_t)((((c0_ & 3) ^ ((c0_ >> 3) & 3))) * 8);
    const int64_t soff1 = (int64_t)(c1_ >> 2) * K_DIM + (int64_t)((((c1_ & 3) ^ ((c1_ >> 3) & 3))) * 8);
    const int l0 = (c0_ & ~63) * 8;
    const int l1 = (c1_ & ~63) * 8;

    // ds_read fragment offsets (region-relative, shorts)
    int offA[8], offB[4];
#pragma unroll
    for (int m = 0; m < 8; ++m) {
        const int row = wm * 128 + m * 16 + (lane & 15);
        offA[m] = row * 32 + (((lane >> 4) ^ (row >> 1)) & 3) * 8;
    }
#pragma unroll
    for (int n = 0; n < 4; ++n) {
        const int row = wn * 64 + n * 16 + (lane & 15);
        offB[n] = row * 32 + (((lane >> 4) ^ (row >> 1)) & 3) * 8;
    }

    f32x4 acc[8][4] = {};
    bf16x8 aF[4], bF[4];

#define REGP(buf, mat, kh) (smem + (buf) * 32768 + (mat) * 16384 + (kh) * 8192)
#define LOAD_A(buf, kh, mh) { \
    const unsigned short* r_ = REGP(buf, 0, kh); \
    _Pragma("unroll") for (int m_ = 0; m_ < 4; ++m_) \
        aF[m_] = *reinterpret_cast<const bf16x8*>(r_ + offA[(mh) * 4 + m_]); }
#define LOAD_B(buf, kh) { \
    const unsigned short* r_ = REGP(buf, 1, kh); \
    _Pragma("unroll") for (int n_ = 0; n_ < 4; ++n_) \
        bF[n_] = *reinterpret_cast<const bf16x8*>(r_ + offB[n_]); }
#define MFMA16(mh) { \
    _Pragma("unroll") for (int m_ = 0; m_ < 4; ++m_) \
    _Pragma("unroll") for (int n_ = 0; n_ < 4; ++n_) \
        acc[(mh) * 4 + m_][n_] = __builtin_amdgcn_mfma_f32_16x16x32_bf16(aF[m_], bF[n_], acc[(mh) * 4 + m_][n_], 0, 0, 0); }
#define STG(buf, mat, kh, gt) stg2(REGP(buf, mat, kh), (gt), soff0, soff1, l0, l1)
#define VM6() asm volatile("s_waitcnt vmcnt(6)" ::: "memory")
// R6 change: no explicit lgkmcnt(0)/sched_barrier — compiler emits fine-grained
// lgkmcnt(N) per MFMA operand dependency (m97/r109: near-optimal).
#define PH_PRE()  { __builtin_amdgcn_s_barrier(); \
                    __builtin_amdgcn_s_setprio(1); }
#define PH_POST() { __builtin_amdgcn_s_setprio(0); \
                    __builtin_amdgcn_s_barrier(); }

    // ---- prologue: tile0 all 4 halves, vmcnt(4), tile1 first 3 halves, vmcnt(6) ----
    STG(0, 1, 0, Bg);            // t0.B-kh0
    STG(0, 0, 0, Ag);            // t0.A-kh0
    STG(0, 1, 1, Bg + 32);       // t0.B-kh1
    STG(0, 0, 1, Ag + 32);       // t0.A-kh1
    asm volatile("s_waitcnt vmcnt(4)" ::: "memory");
    STG(1, 1, 0, Bg + 64);       // t1.B-kh0
    STG(1, 0, 0, Ag + 64);       // t1.A-kh0
    STG(1, 1, 1, Bg + 96);       // t1.B-kh1
    asm volatile("s_waitcnt vmcnt(6)" ::: "memory");
    __builtin_amdgcn_s_barrier();

    // ---- main loop: iter i computes tiles 2i (buf0) and 2i+1 (buf1) ----
    for (int i = 0; i < NITER - 1; ++i) {
        const unsigned short* At1 = Ag + (2 * i + 1) * 64;
        const unsigned short* At2 = Ag + (2 * i + 2) * 64;
        const unsigned short* At3 = Ag + (2 * i + 3) * 64;
        const unsigned short* Bt2 = Bg + (2 * i + 2) * 64;
        const unsigned short* Bt3 = Bg + (2 * i + 3) * 64;

        // ph1: compute t2i kh0 mh0; stage buf1.A-kh1 <- t(2i+1).A-kh1
        LOAD_A(0, 0, 0); LOAD_B(0, 0);
        STG(1, 0, 1, At1 + 32);
        PH_PRE(); MFMA16(0); PH_POST();
        // ph2: kh0 mh1; stage buf0.B-kh0 <- t(2i+2)  (freed by ph1's B read)
        LOAD_A(0, 0, 1);
        STG(0, 1, 0, Bt2);
        PH_PRE(); MFMA16(1); PH_POST();
        // ph3: kh1 mh0; stage buf0.A-kh0 (freed ph2)
        LOAD_A(0, 1, 0); LOAD_B(0, 1);
        STG(0, 0, 0, At2);
        PH_PRE(); MFMA16(0); PH_POST();
        // ph4: kh1 mh1; stage buf0.B-kh1 (freed ph3); counted vmcnt -> t(2i+1) landed
        LOAD_A(0, 1, 1);
        STG(0, 1, 1, Bt2 + 32);
        VM6();
        PH_PRE(); MFMA16(1); PH_POST();
        // ph5: compute t(2i+1) kh0 mh0 (buf1); stage buf0.A-kh1 (freed ph4)
        LOAD_A(1, 0, 0); LOAD_B(1, 0);
        STG(0, 0, 1, At2 + 32);
        PH_PRE(); MFMA16(0); PH_POST();
        // ph6: kh0 mh1; stage buf1.B-kh0 <- t(2i+3) (freed ph5)
        LOAD_A(1, 0, 1);
        STG(1, 1, 0, Bt3);
        PH_PRE(); MFMA16(1); PH_POST();
        // ph7: kh1 mh0; stage buf1.A-kh0 (freed ph6)
        LOAD_A(1, 1, 0); LOAD_B(1, 1);
        STG(1, 0, 0, At3);
        PH_PRE(); MFMA16(0); PH_POST();
        // ph8: kh1 mh1; stage buf1.B-kh1 (freed ph7); counted vmcnt -> t(2i+2) landed
        LOAD_A(1, 1, 1);
        STG(1, 1, 1, Bt3 + 32);
        VM6();
        PH_PRE(); MFMA16(1); PH_POST();
    }

    // ---- final iteration (tiles 30, 31): only t31.A-kh1 left to stage ----
    {
        LOAD_A(0, 0, 0); LOAD_B(0, 0);
        STG(1, 0, 1, Ag + 31 * 64 + 32);
        PH_PRE(); MFMA16(0); PH_POST();
        LOAD_A(0, 0, 1);
        PH_PRE(); MFMA16(1); PH_POST();
        LOAD_A(0, 1, 0); LOAD_B(0, 1);
        PH_PRE(); MFMA16(0); PH_POST();
        LOAD_A(0, 1, 1);
        asm volatile("s_waitcnt vmcnt(0)" ::: "memory");
        PH_PRE(); MFMA16(1); PH_POST();
        LOAD_A(1, 0, 0); LOAD_B(1, 0);
        PH_PRE(); MFMA16(0); PH_POST();
        LOAD_A(1, 0, 1);
        PH_PRE(); MFMA16(1); PH_POST();
        LOAD_A(1, 1, 0); LOAD_B(1, 1);
        PH_PRE(); MFMA16(0); PH_POST();
        LOAD_A(1, 1, 1);
        PH_PRE(); MFMA16(1);
        __builtin_amdgcn_s_setprio(0);
    }

    // ---- fused LSTM epilogue ----
    const int h = (n0 >> 2) + wn * 16 + (lane & 15);
    const float bi  = bx[h]            + bh[h];
    const float bff = bx[HIDN + h]     + bh[HIDN + h];
    const float bc  = bx[2 * HIDN + h] + bh[2 * HIDN + h];
    const float bo  = bx[3 * HIDN + h] + bh[3 * HIDN + h];

#pragma unroll
    for (int m = 0; m < 8; ++m) {
        const int rowb = m0 + wm * 128 + m * 16 + ((lane >> 4) << 2);
#pragma unroll
        for (int r = 0; r < 4; ++r) {
            const int row = rowb + r;
            const float gi = acc[m][0][r] + bi;
            const float gf = acc[m][1][r] + bff;
            const float gc = acc[m][2][r] + bc;
            const float go = acc[m][3][r] + bo;
            const float si = 1.f / (1.f + __expf(-gi));
            const float sf = 1.f / (1.f + __expf(-gf));
            const float tc = 1.f - 2.f / (__expf(2.f * gc) + 1.f);
            const float so = 1.f / (1.f + __expf(-go));
            const float c0v = c0[(int64_t)row * HIDN + h];
            const float c1 = sf * c0v + si * tc;
            const float th = 1.f - 2.f / (__expf(2.f * c1) + 1.f);
            out[(int64_t)row * HIDN + h] = so * th;                        // h1
            out[(int64_t)M_ROWS * HIDN + (int64_t)row * HIDN + h] = c1;    // c1
        }
    }
}

extern "C" void kernel_launch(void* const* d_in, const int* in_sizes, int n_in,
                              void* d_out, int out_size, void* d_ws, size_t ws_size,
                              hipStream_t stream) {
    const float* x  = (const float*)d_in[0];
    const float* h0 = (const float*)d_in[1];
    const float* c0 = (const float*)d_in[2];
    const float* Wx = (const float*)d_in[3];
    const float* bx = (const float*)d_in[4];
    const float* Wh = (const float*)d_in[5];
    const float* bh = (const float*)d_in[6];
    float* out = (float*)d_out;

    unsigned short* A = (unsigned short*)d_ws;                       // 33.5 MB
    unsigned short* B = A + (size_t)M_ROWS * K_DIM;                  // 16.8 MB

    pack_kernel<<<dim3(24576), dim3(256), 0, stream>>>(x, h0, Wx, Wh, A, B);
    lstm_gemm_kernel<<<dim3(512), dim3(512), 0, stream>>>(A, B, bx, bh, c0, out);
}